// Round 2
// baseline (961.830 us; speedup 1.0000x reference)
//
#include <hip/hip_runtime.h>
#include <cstdint>

#define F_IN 256
#define F_H  16
#define F_C  40

// ---------------------------------------------------------------------------
// K1: t1[N,16] = x[N,256] @ W1[256,16]
// block = 256 threads, 16 nodes per block. W1 + x-tile staged in LDS.
// ---------------------------------------------------------------------------
__global__ __launch_bounds__(256) void gemm1_kernel(
    const float* __restrict__ x, const float* __restrict__ W1,
    float* __restrict__ t1, int N) {
  __shared__ float wlds[F_IN * F_H];   // 16 KB, layout [k][f] (same as W1)
  __shared__ float xlds[16 * 260];     // 16 rows, padded stride 260 (16B-aligned, 2-way max)
  const int tid = threadIdx.x;
  const int nodeBase = blockIdx.x * 16;

  for (int i = tid; i < F_IN * F_H; i += 256) wlds[i] = W1[i];

  // stage 16 rows x 256 floats as float4 (coalesced)
  const float4* x4 = reinterpret_cast<const float4*>(x) + (size_t)nodeBase * (F_IN / 4);
  for (int i = tid; i < 16 * (F_IN / 4); i += 256) {
    int r = i >> 6;            // /64
    int c4 = i & 63;
    float4 v = make_float4(0.f, 0.f, 0.f, 0.f);
    if (nodeBase + r < N) v = x4[(size_t)r * (F_IN / 4) + c4];
    *reinterpret_cast<float4*>(&xlds[r * 260 + c4 * 4]) = v;
  }
  __syncthreads();

  const int r = tid >> 4;      // node within tile
  const int f = tid & 15;      // output feature
  const float* xr = &xlds[r * 260];
  float acc = 0.f;
#pragma unroll 8
  for (int k = 0; k < F_IN; ++k) acc = fmaf(xr[k], wlds[k * F_H + f], acc);
  if (nodeBase + r < N) t1[(size_t)nodeBase * F_H + tid] = acc;  // coalesced
}

// ---------------------------------------------------------------------------
// K2: scatter layer1 — agg1[dst] += t1[src] * w, 16 feats/edge
// thread = (edge, feat); 16 consecutive threads share one edge
// ---------------------------------------------------------------------------
__global__ __launch_bounds__(256) void scatter1_kernel(
    const float* __restrict__ t1, const int* __restrict__ ei,
    const float* __restrict__ ew, float* __restrict__ agg1, int N, int E) {
  int gid = blockIdx.x * 256 + threadIdx.x;
  int e = gid >> 4;
  int f = gid & 15;
  if (e >= E) return;
  int s = ei[e];
  int d = ei[E + e];
  if ((unsigned)s >= (unsigned)N || (unsigned)d >= (unsigned)N) return;
  float v = t1[(size_t)s * F_H + f] * ew[e];
  unsafeAtomicAdd(&agg1[(size_t)d * F_H + f], v);
}

// ---------------------------------------------------------------------------
// K3: h2[N,40] = relu(agg1 + b1) @ W2[16,40]
// block = 320 threads (5 waves), 8 nodes per block
// ---------------------------------------------------------------------------
__global__ __launch_bounds__(320) void gemm2_kernel(
    const float* __restrict__ agg1, const float* __restrict__ b1,
    const float* __restrict__ W2, float* __restrict__ h2, int N) {
  __shared__ float w2lds[F_H * F_C];   // 640 floats
  __shared__ float alds[8 * F_H];      // relu(agg1+b1) for 8 nodes
  const int tid = threadIdx.x;
  const int nodeBase = blockIdx.x * 8;

  for (int i = tid; i < F_H * F_C; i += 320) w2lds[i] = W2[i];
  if (tid < 8 * F_H) {
    int node = nodeBase + (tid >> 4);
    float v = 0.f;
    if (node < N) v = agg1[(size_t)nodeBase * F_H + tid] + b1[tid & 15];
    alds[tid] = v > 0.f ? v : 0.f;
  }
  __syncthreads();

  const int ln = tid / F_C;            // local node 0..7
  const int f = tid - ln * F_C;        // feature 0..39
  const int node = nodeBase + ln;
  if (node >= N) return;
  float acc = 0.f;
#pragma unroll
  for (int k = 0; k < F_H; ++k) acc = fmaf(alds[ln * F_H + k], w2lds[k * F_C + f], acc);
  h2[(size_t)nodeBase * F_C + tid] = acc;  // coalesced
}

// ---------------------------------------------------------------------------
// K4: scatter layer2 — out[dst] += h2[src] * w, 40 feats/edge
// block = 320 threads, 8 edges per block
// ---------------------------------------------------------------------------
__global__ __launch_bounds__(320) void scatter2_kernel(
    const float* __restrict__ h2, const int* __restrict__ ei,
    const float* __restrict__ ew, float* __restrict__ out, int N, int E) {
  const int tid = threadIdx.x;
  const int le = tid / F_C;
  const int f = tid - le * F_C;
  const int e = blockIdx.x * 8 + le;
  if (e >= E) return;
  int s = ei[e];
  int d = ei[E + e];
  if ((unsigned)s >= (unsigned)N || (unsigned)d >= (unsigned)N) return;
  float v = h2[(size_t)s * F_C + f] * ew[e];
  unsafeAtomicAdd(&out[(size_t)d * F_C + f], v);
}

// ---------------------------------------------------------------------------
// K5: in-place log_softmax over 40 classes, + b2. 256 nodes per block.
// ---------------------------------------------------------------------------
__global__ __launch_bounds__(256) void lsm_kernel(
    const float* __restrict__ b2, float* __restrict__ out, int N) {
  __shared__ float rows[256 * 41];     // padded stride 41
  __shared__ float mlog[256];
  const int tid = threadIdx.x;
  const int base = blockIdx.x * 256;
  const int nrows = min(256, N - base);
  if (nrows <= 0) return;

  for (int idx = tid; idx < nrows * F_C; idx += 256) {
    int r = idx / F_C;
    int f = idx - r * F_C;
    rows[r * 41 + f] = out[(size_t)base * F_C + idx] + b2[f];
  }
  __syncthreads();

  if (tid < nrows) {
    const float* row = &rows[tid * 41];
    float m = -INFINITY;
#pragma unroll
    for (int f = 0; f < F_C; ++f) m = fmaxf(m, row[f]);
    float s = 0.f;
#pragma unroll
    for (int f = 0; f < F_C; ++f) s += __expf(row[f] - m);
    mlog[tid] = m + __logf(s);
  }
  __syncthreads();

  for (int idx = tid; idx < nrows * F_C; idx += 256) {
    int r = idx / F_C;
    int f = idx - r * F_C;
    out[(size_t)base * F_C + idx] = rows[r * 41 + f] - mlog[r];
  }
}

// ---------------------------------------------------------------------------
extern "C" void kernel_launch(void* const* d_in, const int* in_sizes, int n_in,
                              void* d_out, int out_size, void* d_ws, size_t ws_size,
                              hipStream_t stream) {
  const float* x  = (const float*)d_in[0];
  const int*   ei = (const int*)d_in[1];
  const float* ew = (const float*)d_in[2];
  const float* W1 = (const float*)d_in[3];
  const float* b1 = (const float*)d_in[4];
  const float* W2 = (const float*)d_in[5];
  const float* b2 = (const float*)d_in[6];
  float* out = (float*)d_out;

  const int N = in_sizes[0] / F_IN;
  const int E = in_sizes[2];

  // workspace layout: t1[N*16] | agg1[N*16] | h2[N*40]
  float* t1   = (float*)d_ws;
  float* agg1 = t1 + (size_t)N * F_H;
  float* h2   = agg1 + (size_t)N * F_H;

  hipMemsetAsync(agg1, 0, (size_t)N * F_H * sizeof(float), stream);
  hipMemsetAsync(out, 0, (size_t)N * F_C * sizeof(float), stream);

  gemm1_kernel<<<(N + 15) / 16, 256, 0, stream>>>(x, W1, t1, N);
  scatter1_kernel<<<(E * 16 + 255) / 256, 256, 0, stream>>>(t1, ei, ew, agg1, N, E);
  gemm2_kernel<<<(N + 7) / 8, 320, 0, stream>>>(agg1, b1, W2, h2, N);
  scatter2_kernel<<<(E + 7) / 8, 320, 0, stream>>>(h2, ei, ew, out, N, E);
  lsm_kernel<<<(N + 255) / 256, 256, 0, stream>>>(b2, out, N);
}